// Round 2
// 99.532 us; speedup vs baseline: 1.0043x; 1.0043x over previous
//
#include <hip/hip_runtime.h>

#define E_DIM 256
#define S_DIM 2048
#define B_DIM 8

typedef unsigned short u16;
typedef __bf16 bf16x8 __attribute__((ext_vector_type(8)));
typedef float f32x4 __attribute__((ext_vector_type(4)));
typedef u16 u16x8 __attribute__((ext_vector_type(8)));

__device__ inline u16 f2bf(float f) {
  unsigned u = __builtin_bit_cast(unsigned, f);
  return (u16)((u + 0x7FFF + ((u >> 16) & 1)) >> 16);  // RTNE, finite inputs
}
__device__ inline float bf2f(u16 v) {
  unsigned u = ((unsigned)v) << 16;
  return __builtin_bit_cast(float, u);
}

// ---------------------------------------------------------------------------
// Prep: Wq, Wo (fp32 [f][e]) -> bf16 [f][e]
// ---------------------------------------------------------------------------
__global__ __launch_bounds__(256) void convert_w(
    const float* __restrict__ Wq, const float* __restrict__ Wo,
    u16* __restrict__ Wqb, u16* __restrict__ Wob) {
  int idx = (blockIdx.x * 256 + threadIdx.x) * 4;  // grid 128 -> 131072 elems
  const float* src;
  u16* dst;
  if (idx < 65536) { src = Wq + idx; dst = Wqb + idx; }
  else { src = Wo + (idx - 65536); dst = Wob + (idx - 65536); }
  float4 v = *(const float4*)src;
  *(ushort4*)dst = make_ushort4(f2bf(v.x), f2bf(v.y), f2bf(v.z), f2bf(v.w));
}

// ---------------------------------------------------------------------------
// Fused: one block = (b, 64-s tile), 1024 threads (16 waves), grid 256 = 1/CU.
// 4 barriers.
//  P0: stage xt[r][e] bf16, r=0..79 (t = s0-4+r; r>=72 or OOB -> 0)
//  P1: q = xt.Wq^T + bq (MFMA, M=80 N=256 K=256) -> qt bf16 rows 0..71
//      waves 0-7: m-frags {0,1,2} x f-slice; waves 8-15: m-frags {3,4}.
//  PE: banded energies via MFMA (waves 0..7): E[s][l] = qt[s+4].qt[s+l].
//      wave = (band a = w>>1, half h = w&1): m-frag rows 16a+4+lm;
//      n-frag rows 16a+8h+lm. Banded C elems scattered RAW to eb[64][9].
//  P3: softmax (redundant per-thread, scale 1/24) + pooled[s][e] =
//      sum_l w[s][l]*xt[s+l][e]  (bf16, aliases qt)
//  P4: out[b][f][s] = (pooled.Wo^T + bo)/9 (MFMA, M=64 N=256 K=256)
// Zero-staged OOB rows give q_row = bq and zero-padded pooling exactly.
// ---------------------------------------------------------------------------
#define TS 64
#define QR 72      // valid q rows: t = s0-4 .. s0+67
#define XROWS 80   // padded to 5 m-frags
#define XSTR 264   // u16 row stride (132 dw: b128 frag reads 2-way = free)
#define QSTR 264
#define PSTR 264

template <int NM>
__device__ inline void p1_compute(const u16* __restrict__ xt,
                                  const u16* __restrict__ Wqb,
                                  const float* __restrict__ bq,
                                  u16* __restrict__ qt,
                                  int mbase, int fs, int lm, int lk) {
  const f32x4 zero = {0.f, 0.f, 0.f, 0.f};
  f32x4 acc[NM][2];
#pragma unroll
  for (int i = 0; i < NM; ++i)
#pragma unroll
    for (int j = 0; j < 2; ++j) acc[i][j] = zero;
#pragma unroll
  for (int k0 = 0; k0 < 8; ++k0) {
    bf16x8 af[NM], bfr[2];
#pragma unroll
    for (int i = 0; i < NM; ++i)
      af[i] = *(const bf16x8*)&xt[(mbase + i * 16 + lm) * XSTR + k0 * 32 + lk * 8];
#pragma unroll
    for (int j = 0; j < 2; ++j)
      bfr[j] = *(const bf16x8*)&Wqb[(size_t)(fs * 32 + j * 16 + lm) * E_DIM +
                                    k0 * 32 + lk * 8];
#pragma unroll
    for (int i = 0; i < NM; ++i)
#pragma unroll
      for (int j = 0; j < 2; ++j)
        acc[i][j] = __builtin_amdgcn_mfma_f32_16x16x32_bf16(af[i], bfr[j], acc[i][j], 0, 0, 0);
  }
#pragma unroll
  for (int j = 0; j < 2; ++j) {
    int f = fs * 32 + j * 16 + lm;
    float bv = bq[f];
#pragma unroll
    for (int i = 0; i < NM; ++i) {
      int row = mbase + i * 16 + lk * 4;
#pragma unroll
      for (int r2 = 0; r2 < 4; ++r2)
        if (row + r2 < QR) qt[(row + r2) * QSTR + f] = f2bf(acc[i][j][r2] + bv);
    }
  }
}

__global__ __launch_bounds__(1024) void fused_attn(
    const float* __restrict__ x, const u16* __restrict__ Wqb,
    const float* __restrict__ bq, const u16* __restrict__ Wob,
    const float* __restrict__ bo, float* __restrict__ out) {
  // LDS: xt 42240 | qt 38016 (pooled 33792 aliases) | eb 2304 = 82560 B
  __shared__ __align__(16) char smem[82560];
  u16* xt = (u16*)smem;
  u16* qt = (u16*)(smem + 42240);
  u16* pooled = qt;
  float* eb = (float*)(smem + 80256);  // [64][9] RAW energies

  const int tid = threadIdx.x;
  const int s0 = blockIdx.x * TS;
  const int b = blockIdx.y;
  const int wave = tid >> 6, lane = tid & 63;
  const int lm = lane & 15, lk = lane >> 4;

  // ---- P0: stage xt. tid = eg*128 + r (eg = 32-e slice, r = row) ----
  {
    const int eg = tid >> 7;   // 0..7
    const int r = tid & 127;   // row; active < 80 (lanes consecutive rows)
    if (r < XROWS) {
      const int t = s0 - 4 + r;
      const bool v = (r < QR) && (t >= 0) && (t < S_DIM);
      const float* __restrict__ xb = x + (size_t)b * E_DIM * S_DIM + t;
      const int ebase = eg * 32;
#pragma unroll
      for (int c = 0; c < 4; ++c) {
        u16x8 v8;
#pragma unroll
        for (int u = 0; u < 8; ++u) {
          float xv = v ? xb[(size_t)(ebase + c * 8 + u) * S_DIM] : 0.f;
          v8[u] = f2bf(xv);
        }
        *(u16x8*)&xt[r * XSTR + ebase + c * 8] = v8;
      }
    }
  }
  __syncthreads();

  // ---- P1: K1 MFMA -> qt rows 0..71 (M=80, 16 waves) ----
  {
    const int mh = wave >> 3;  // 0: m-frags 0..2, 1: m-frags 3..4
    const int fs = wave & 7;   // 32-f slice
    if (mh == 0)
      p1_compute<3>(xt, Wqb, bq, qt, 0, fs, lm, lk);
    else
      p1_compute<2>(xt, Wqb, bq, qt, 48, fs, lm, lk);
  }
  __syncthreads();

  // ---- PE: banded energies via MFMA (waves 0..7), RAW -> eb ----
  if (wave < 8) {
    const int a = wave >> 1;            // s-band: s in [16a, 16a+16)
    const int h = wave & 1;             // half: n-frag base 16a + 8h
    const int nb = 16 * a + 8 * h;
    const f32x4 zero = {0.f, 0.f, 0.f, 0.f};
    f32x4 acc = zero;
#pragma unroll
    for (int k0 = 0; k0 < 8; ++k0) {
      bf16x8 af = *(const bf16x8*)&qt[(16 * a + 4 + lm) * QSTR + k0 * 32 + lk * 8];
      bf16x8 bf_ = *(const bf16x8*)&qt[(nb + lm) * QSTR + k0 * 32 + lk * 8];
      acc = __builtin_amdgcn_mfma_f32_16x16x32_bf16(af, bf_, acc, 0, 0, 0);
    }
    // scatter banded C elements: C row = s (local to band), col idx = lm
#pragma unroll
    for (int r = 0; r < 4; ++r) {
      int s = 16 * a + lk * 4 + r;      // output s in 0..63
      int nrow = nb + lm;               // qt row of this C column
      int l = nrow - s;
      bool ok = (l >= 0) && (l <= 8) && (h == 0 || nrow >= 16 * a + 16);
      if (ok) eb[s * 9 + l] = acc[r];
    }
  }
  __syncthreads();

  // ---- P3: per-thread softmax + pooled[s][e] (overlays qt) ----
  {
    const int s = lane;        // tid & 63 == lane (64-aligned waves)
    const int ep = wave;       // 16 e each
    float e9[9];
#pragma unroll
    for (int l = 0; l < 9; ++l) e9[l] = eb[s * 9 + l] * (1.0f / 24.0f);
    float m = e9[0];
#pragma unroll
    for (int l = 1; l < 9; ++l) m = fmaxf(m, e9[l]);
    float sum = 0.f;
#pragma unroll
    for (int l = 0; l < 9; ++l) { e9[l] = __expf(e9[l] - m); sum += e9[l]; }
    float inv = 1.0f / sum;
    float w9[9];
#pragma unroll
    for (int l = 0; l < 9; ++l) w9[l] = e9[l] * inv;
#pragma unroll
    for (int c = 0; c < 2; ++c) {
      int e8 = ep * 16 + c * 8;
      float o[8];
#pragma unroll
      for (int u = 0; u < 8; ++u) o[u] = 0.f;
#pragma unroll
      for (int l = 0; l < 9; ++l) {
        u16x8 xv = *(const u16x8*)&xt[(s + l) * XSTR + e8];
#pragma unroll
        for (int u = 0; u < 8; ++u) o[u] += w9[l] * bf2f(xv[u]);
      }
      u16x8 pv;
#pragma unroll
      for (int u = 0; u < 8; ++u) pv[u] = f2bf(o[u]);
      *(u16x8*)&pooled[s * PSTR + e8] = pv;
    }
  }
  __syncthreads();

  // ---- P4: K3 MFMA -> out[b][f][s] (M=64, 16 waves) ----
  {
    const int mh = wave >> 3;  // m-frags {0,1} or {2,3}
    const int fs = wave & 7;
    const f32x4 zero = {0.f, 0.f, 0.f, 0.f};
    f32x4 acc[2][2];
#pragma unroll
    for (int i = 0; i < 2; ++i)
#pragma unroll
      for (int j = 0; j < 2; ++j) acc[i][j] = zero;
#pragma unroll
    for (int k0 = 0; k0 < 8; ++k0) {
      bf16x8 af[2], bfr[2];
#pragma unroll
      for (int i = 0; i < 2; ++i)
        af[i] = *(const bf16x8*)&pooled[((mh * 2 + i) * 16 + lm) * PSTR + k0 * 32 + lk * 8];
#pragma unroll
      for (int j = 0; j < 2; ++j)
        bfr[j] = *(const bf16x8*)&Wob[(size_t)(fs * 32 + j * 16 + lm) * E_DIM +
                                      k0 * 32 + lk * 8];
#pragma unroll
      for (int i = 0; i < 2; ++i)
#pragma unroll
        for (int j = 0; j < 2; ++j)
          acc[i][j] = __builtin_amdgcn_mfma_f32_16x16x32_bf16(af[i], bfr[j], acc[i][j], 0, 0, 0);
    }
#pragma unroll
    for (int j = 0; j < 2; ++j) {
      int f = fs * 32 + j * 16 + lm;
      float bv = bo[f];
#pragma unroll
      for (int i = 0; i < 2; ++i) {
        int s = s0 + (mh * 2 + i) * 16 + lk * 4;
        float4 w = make_float4((acc[i][j][0] + bv) * (1.0f / 9.0f),
                               (acc[i][j][1] + bv) * (1.0f / 9.0f),
                               (acc[i][j][2] + bv) * (1.0f / 9.0f),
                               (acc[i][j][3] + bv) * (1.0f / 9.0f));
        *(float4*)&out[((size_t)b * E_DIM + f) * S_DIM + s] = w;
      }
    }
  }
}

// ---------------------------------------------------------------------------
extern "C" void kernel_launch(void* const* d_in, const int* in_sizes, int n_in,
                              void* d_out, int out_size, void* d_ws, size_t ws_size,
                              hipStream_t stream) {
  const float* x = (const float*)d_in[0];
  const float* Wq = (const float*)d_in[1];
  const float* bq = (const float*)d_in[2];
  const float* Wo = (const float*)d_in[3];
  const float* bo = (const float*)d_in[4];
  float* out = (float*)d_out;

  u16* Wqb = (u16*)d_ws;
  u16* Wob = Wqb + 65536;

  convert_w<<<128, 256, 0, stream>>>(Wq, Wo, Wqb, Wob);
  fused_attn<<<dim3(S_DIM / TS, B_DIM), 1024, 0, stream>>>(x, Wqb, bq, Wob, bo, out);
}